// Round 3
// baseline (1750.262 us; speedup 1.0000x reference)
//
#include <hip/hip_runtime.h>
#include <hip/hip_bf16.h>
#include <stdint.h>

// Problem constants (fixed by the reference)
#define B_   4
#define H_   8
#define SQ_  2048
#define SK_  512
#define DM_  4096
#define DK_  512

typedef __bf16 bf16;
typedef __bf16 bf16x8 __attribute__((ext_vector_type(8)));
typedef float  fx4    __attribute__((ext_vector_type(4)));

// address-space-qualified pointer types for global_load_lds
typedef __attribute__((address_space(1))) void gv_t;   // global
typedef __attribute__((address_space(3))) void lv_t;   // LDS

// ---------------------------------------------------------------------------
// Dtype sniffer (unchanged). flag=1 -> external tensors are fp32.
__global__ void sniff_dtype(const uint32_t* __restrict__ q, int* __restrict__ flag)
{
    const int l = threadIdx.x;  // 64 lanes
    int cnt = 0;
    #pragma unroll
    for (int i = 0; i < 4; ++i) {
        const uint32_t u = q[l * 4 + i];
        const int e = (u >> 7) & 0xFF;
        cnt += (e >= 100 && e <= 135) ? 1 : 0;
    }
    #pragma unroll
    for (int s = 1; s < 64; s <<= 1) cnt += __shfl_xor(cnt, s);
    if (l == 0) *flag = (cnt < 150) ? 1 : 0;
}

// ---------------------------------------------------------------------------
// One-time dtype normalization: fp32 -> bf16 (or bf16 passthrough copy).
__global__ __launch_bounds__(256) void cvt_to_bf16(
    const void* __restrict__ in, bf16* __restrict__ out, const int* __restrict__ flagp)
{
    const size_t i = ((size_t)blockIdx.x * 256 + threadIdx.x) * 8;
    if (*flagp) {
        const float4* p = (const float4*)((const float*)in + i);
        const float4 u0 = p[0], u1 = p[1];
        bf16x8 v;
        v[0] = (bf16)u0.x; v[1] = (bf16)u0.y; v[2] = (bf16)u0.z; v[3] = (bf16)u0.w;
        v[4] = (bf16)u1.x; v[5] = (bf16)u1.y; v[6] = (bf16)u1.z; v[7] = (bf16)u1.w;
        *(bf16x8*)(out + i) = v;
    } else {
        *(bf16x8*)(out + i) = *(const bf16x8*)((const bf16*)in + i);
    }
}

// ---------------------------------------------------------------------------
// 128^2-tile GEMM (verified rounds 0-1). Kept for the three M=2048 projections
// where a 256^2 grid would leave half the CUs idle.
__global__ __launch_bounds__(256, 3) void gemm_bt(
    const bf16* __restrict__ A, const bf16* __restrict__ Bt,
    void* __restrict__ Cv, const void* __restrict__ biasv,
    int K, int lda, int ldb, int ldc, float alpha,
    long long sAb, long long sAh, long long sBb, long long sBh,
    long long sCb, long long sCh,
    const int* __restrict__ flagp, int ebits)
{
    __shared__ bf16 sA[128 * 64];
    __shared__ bf16 sB[128 * 64];

    const int fl = ebits ? *flagp : 0;
    const bool bias32 = fl && (ebits & 1);
    const bool c32    = fl && (ebits & 2);

    const int z = blockIdx.z;
    const int bz = z >> 3, hz = z & 7;
    const bf16* Ab = A  + (size_t)bz * sAb + (size_t)hz * sAh;
    const bf16* Bb = Bt + (size_t)bz * sBb + (size_t)hz * sBh;
    const size_t offC = (size_t)bz * sCb + (size_t)hz * sCh;

    const int n0 = blockIdx.x * 128;
    const int m0 = blockIdx.y * 128;

    const int t = threadIdx.x;
    const int w = t >> 6, l = t & 63;
    const int lrow = l >> 3, lcol = l & 7;
    const int wm = (w >> 1) * 64, wn = (w & 1) * 64;
    const int ml = l & 15, quad = l >> 4;

    const bf16* pa[4];
    const bf16* pb[4];
    #pragma unroll
    for (int i = 0; i < 4; ++i) {
        const int c = w * 4 + i;
        const int r = c * 8 + lrow;
        const int jj = lcol ^ (r & 7);
        pa[i] = Ab + (size_t)(m0 + r) * lda + jj * 8;
        pb[i] = Bb + (size_t)(n0 + r) * ldb + jj * 8;
    }

    fx4 acc[4][4];
    const fx4 zero = {0.f, 0.f, 0.f, 0.f};
    #pragma unroll
    for (int i = 0; i < 4; ++i)
        #pragma unroll
        for (int j = 0; j < 4; ++j) acc[i][j] = zero;

    for (int kt = 0; kt < K; kt += 64) {
        #pragma unroll
        for (int i = 0; i < 4; ++i) {
            const int c = w * 4 + i;
            __builtin_amdgcn_global_load_lds((gv_t*)(pa[i] + kt), (lv_t*)(sA + c * 512), 16, 0, 0);
            __builtin_amdgcn_global_load_lds((gv_t*)(pb[i] + kt), (lv_t*)(sB + c * 512), 16, 0, 0);
        }
        __syncthreads();

        #pragma unroll
        for (int kk = 0; kk < 64; kk += 32) {
            bf16x8 af[4], bfr[4];
            const int jbase = (kk >> 3) + quad;
            #pragma unroll
            for (int mi = 0; mi < 4; ++mi) {
                const int r = wm + mi * 16 + ml;
                af[mi] = *(const bf16x8*)&sA[r * 64 + ((jbase ^ (r & 7)) << 3)];
            }
            #pragma unroll
            for (int ni = 0; ni < 4; ++ni) {
                const int r = wn + ni * 16 + ml;
                bfr[ni] = *(const bf16x8*)&sB[r * 64 + ((jbase ^ (r & 7)) << 3)];
            }
            #pragma unroll
            for (int mi = 0; mi < 4; ++mi)
                #pragma unroll
                for (int ni = 0; ni < 4; ++ni)
                    acc[mi][ni] = __builtin_amdgcn_mfma_f32_16x16x32_bf16(
                        af[mi], bfr[ni], acc[mi][ni], 0, 0, 0);
        }
        __syncthreads();
    }

    #pragma unroll
    for (int ni = 0; ni < 4; ++ni) {
        const int cg = n0 + wn + ni * 16 + ml;
        const float bv = biasv ? (bias32 ? ((const float*)biasv)[cg] : (float)((const bf16*)biasv)[cg]) : 0.f;
        #pragma unroll
        for (int mi = 0; mi < 4; ++mi) {
            const int rg = m0 + wm + mi * 16 + quad * 4;
            #pragma unroll
            for (int r = 0; r < 4; ++r) {
                const float val = acc[mi][ni][r] * alpha + bv;
                const size_t idx = offC + (size_t)(rg + r) * ldc + cg;
                if (c32) ((float*)Cv)[idx] = val;
                else     ((bf16*)Cv)[idx] = (bf16)val;
            }
        }
    }
}

// ---------------------------------------------------------------------------
// 256^2-tile 8-phase pipelined GEMM (T3+T4+T5 port, plain HIP).
// 512 threads = 8 waves (2 wave-rows x 4 wave-cols); per-wave C = 128x64.
// BK=64; LDS = 2 dbuf x (A 256x64 + B 256x64) bf16 = 128 KiB -> 1 WG/CU.
// Schedule per K-tile t (reading buf[t&1]):
//   4 phases: {12 ds_read (quadrant) ; s_barrier ; setprio(1) 16 MFMA
//              setprio(0) ; s_barrier}
//   boundary: issue tile t+2 into buf[t&1] (dead: all reads drained before the
//   last barrier), then COUNTED s_waitcnt vmcnt(8) -> tile t+1's 8 loads have
//   landed while tile t+2's 8 stay in flight across the barrier. vmcnt never
//   drains to 0 in the main loop (T4). Raw asm s_barrier (+ "memory" clobber)
//   everywhere: __syncthreads would force vmcnt(0) and kill the pipeline.
// LDS layout + XOR slot swizzle + fragment math identical to gemm_bt
// (measured 0 bank conflicts), extended to 32 staging chunks.
#define ISSUE_TILE(tt, bb)                                                        \
    do {                                                                          \
        _Pragma("unroll")                                                         \
        for (int i_ = 0; i_ < 4; ++i_) {                                          \
            const int c_ = w * 4 + i_;                                            \
            __builtin_amdgcn_global_load_lds((gv_t*)(pa[i_] + (size_t)(tt) * 64), \
                (lv_t*)(&sm[bb][0][c_ * 512]), 16, 0, 0);                         \
            __builtin_amdgcn_global_load_lds((gv_t*)(pb[i_] + (size_t)(tt) * 64), \
                (lv_t*)(&sm[bb][1][c_ * 512]), 16, 0, 0);                         \
        }                                                                         \
    } while (0)

__global__ __launch_bounds__(512, 2) void gemm256(
    const bf16* __restrict__ A, const bf16* __restrict__ Bt,
    void* __restrict__ Cv, const void* __restrict__ biasv,
    int K, int lda, int ldb, int ldc, float alpha,
    long long sAb, long long sAh, long long sBb, long long sBh,
    long long sCb, long long sCh,
    const int* __restrict__ flagp, int ebits)
{
    __shared__ bf16 sm[2][2][256 * 64];   // [buf][A/B][tile] = 128 KiB

    const int fl = ebits ? *flagp : 0;
    const bool bias32 = fl && (ebits & 1);
    const bool c32    = fl && (ebits & 2);

    // ---- XCD-bijective block swizzle (all grids here are %8==0) ----
    const int gX = gridDim.x, gY = gridDim.y;
    int idx = (blockIdx.z * gY + blockIdx.y) * gX + blockIdx.x;
    const int nwg = gX * gY * gridDim.z;
    if ((nwg & 7) == 0) idx = (idx & 7) * (nwg >> 3) + (idx >> 3);
    const int bx = idx % gX;
    const int tmpi = idx / gX;
    const int by = tmpi % gY;
    const int z  = tmpi / gY;

    const int bz = z >> 3, hz = z & 7;
    const bf16* Ab = A  + (size_t)bz * sAb + (size_t)hz * sAh;
    const bf16* Bb = Bt + (size_t)bz * sBb + (size_t)hz * sBh;
    const size_t offC = (size_t)bz * sCb + (size_t)hz * sCh;

    const int n0 = bx * 256;
    const int m0 = by * 256;

    const int t  = threadIdx.x;
    const int w  = t >> 6, l = t & 63;
    const int lrow = l >> 3, lcol = l & 7;          // staging decomposition
    const int wr = w >> 2, wc = w & 3;              // wave grid 2x4
    const int R0 = wr * 128, C0 = wc * 64;          // per-wave C sub-tile
    const int ml = l & 15, quad = l >> 4;           // MFMA fragment lanes

    // per-lane pre-swizzled global source pointers (4 chunks/tensor/wave;
    // 8 waves x 4 chunks x 8 rows = 256 rows)
    const bf16* pa[4];
    const bf16* pb[4];
    #pragma unroll
    for (int i = 0; i < 4; ++i) {
        const int c = w * 4 + i;
        const int r = c * 8 + lrow;
        const int jj = lcol ^ (r & 7);
        pa[i] = Ab + (size_t)(m0 + r) * lda + jj * 8;
        pb[i] = Bb + (size_t)(n0 + r) * ldb + jj * 8;
    }

    fx4 acc[8][4];
    const fx4 zero = {0.f, 0.f, 0.f, 0.f};
    #pragma unroll
    for (int i = 0; i < 8; ++i)
        #pragma unroll
        for (int j = 0; j < 4; ++j) acc[i][j] = zero;

    const int nt = K >> 6;   // K-tiles of 64 (all K here: 512 or 4096)

    // ---- prologue: fill both buffers; keep tile 1's 8 loads in flight ----
    ISSUE_TILE(0, 0);
    ISSUE_TILE(1, 1);
    asm volatile("s_waitcnt vmcnt(8)" ::: "memory");
    asm volatile("s_barrier" ::: "memory");

    for (int tt = 0; tt < nt; ++tt) {
        const int b = tt & 1;
        const bf16* sA = sm[b][0];
        const bf16* sB = sm[b][1];

        #pragma unroll
        for (int q = 0; q < 4; ++q) {
            const int mh = q >> 1, nh = q & 1;      // quadrant of wave sub-tile
            bf16x8 af[4][2], bfr[2][2];
            #pragma unroll
            for (int im = 0; im < 4; ++im)
                #pragma unroll
                for (int kI = 0; kI < 2; ++kI) {
                    const int fr = R0 + (mh * 4 + im) * 16 + ml;
                    const int j  = kI * 4 + quad;
                    af[im][kI] = *(const bf16x8*)&sA[fr * 64 + ((j ^ (fr & 7)) << 3)];
                }
            #pragma unroll
            for (int in = 0; in < 2; ++in)
                #pragma unroll
                for (int kI = 0; kI < 2; ++kI) {
                    const int fr = C0 + (nh * 2 + in) * 16 + ml;
                    const int j  = kI * 4 + quad;
                    bfr[in][kI] = *(const bf16x8*)&sB[fr * 64 + ((j ^ (fr & 7)) << 3)];
                }
            asm volatile("s_barrier" ::: "memory");
            __builtin_amdgcn_s_setprio(1);
            #pragma unroll
            for (int kI = 0; kI < 2; ++kI)
                #pragma unroll
                for (int im = 0; im < 4; ++im)
                    #pragma unroll
                    for (int in = 0; in < 2; ++in)
                        acc[mh * 4 + im][nh * 2 + in] =
                            __builtin_amdgcn_mfma_f32_16x16x32_bf16(
                                af[im][kI], bfr[in][kI],
                                acc[mh * 4 + im][nh * 2 + in], 0, 0, 0);
            __builtin_amdgcn_s_setprio(0);
            asm volatile("s_barrier" ::: "memory");
        }

        if (tt + 1 >= nt) break;
        // buf b is dead: every wave drained its ds_reads (lgkm wait precedes
        // its MFMAs) before arriving at the barrier above.
        if (tt + 2 < nt) {
            ISSUE_TILE(tt + 2, b);
            asm volatile("s_waitcnt vmcnt(8)" ::: "memory");  // tile tt+1 landed; tt+2 in flight
        } else {
            asm volatile("s_waitcnt vmcnt(0)" ::: "memory");  // epilogue drain
        }
        asm volatile("s_barrier" ::: "memory");
    }

    // ---- epilogue: C/D layout col=lane&15, row=(lane>>4)*4+reg ----
    #pragma unroll
    for (int ni = 0; ni < 4; ++ni) {
        const int cg = n0 + C0 + ni * 16 + ml;
        const float bv = biasv ? (bias32 ? ((const float*)biasv)[cg] : (float)((const bf16*)biasv)[cg]) : 0.f;
        #pragma unroll
        for (int mi = 0; mi < 8; ++mi) {
            const int rg = m0 + R0 + mi * 16 + quad * 4;
            #pragma unroll
            for (int r = 0; r < 4; ++r) {
                const float val = acc[mi][ni][r] * alpha + bv;
                const size_t idx = offC + (size_t)(rg + r) * ldc + cg;
                if (c32) ((float*)Cv)[idx] = val;
                else     ((bf16*)Cv)[idx] = (bf16)val;
            }
        }
    }
}

// In-place row softmax, rows of exactly 512 bf16. One wave per row (8 elems/lane).
__global__ __launch_bounds__(256) void softmax512(bf16* __restrict__ buf)
{
    const int row = blockIdx.x * 4 + (threadIdx.x >> 6);
    const int l = threadIdx.x & 63;
    bf16* p = buf + (size_t)row * 512 + l * 8;
    bf16x8 v = *(const bf16x8*)p;
    float f[8];
    float mx = -1e30f;
    #pragma unroll
    for (int j = 0; j < 8; ++j) {
        f[j] = (float)v[j];
        if (!(fabsf(f[j]) < 1e30f)) f[j] = -1e9f;   // NaN/Inf guard
        mx = fmaxf(mx, f[j]);
    }
    #pragma unroll
    for (int s = 1; s < 64; s <<= 1) mx = fmaxf(mx, __shfl_xor(mx, s));
    float sum = 0.f;
    #pragma unroll
    for (int j = 0; j < 8; ++j) { f[j] = __expf(f[j] - mx); sum += f[j]; }
    #pragma unroll
    for (int s = 1; s < 64; s <<= 1) sum += __shfl_xor(sum, s);
    const float inv = 1.f / sum;
    #pragma unroll
    for (int j = 0; j < 8; ++j) v[j] = (bf16)(f[j] * inv);
    *(bf16x8*)p = v;
}

// out[z][d][s] = in[b][s][h*512+d], z = b*8+h. 32x32 tiles via LDS. (internal bf16)
__global__ __launch_bounds__(256) void transpose_heads(
    const bf16* __restrict__ in, bf16* __restrict__ out)
{
    __shared__ bf16 tile[32][33];
    const int z = blockIdx.z, b = z >> 3, h = z & 7;
    const int s0 = blockIdx.x * 32, d0 = blockIdx.y * 32;
    const int tx = threadIdx.x, ty = threadIdx.y;   // 32 x 8
    #pragma unroll
    for (int j = 0; j < 4; ++j) {
        const int s = s0 + ty + j * 8;
        tile[ty + j * 8][tx] = in[(size_t)b * SK_ * DM_ + (size_t)s * DM_ + h * DK_ + d0 + tx];
    }
    __syncthreads();
    #pragma unroll
    for (int j = 0; j < 4; ++j) {
        const int d = d0 + ty + j * 8;
        out[(size_t)z * DK_ * SK_ + (size_t)d * SK_ + s0 + tx] = tile[tx][ty + j * 8];
    }
}

extern "C" void kernel_launch(void* const* d_in, const int* in_sizes, int n_in,
                              void* d_out, int out_size, void* d_ws, size_t ws_size,
                              hipStream_t stream)
{
    const void* query = d_in[0];
    const void* key   = d_in[1];
    const void* value = d_in[2];
    const void* imf   = d_in[3];
    const void* W0 = d_in[4];  const void* b0 = d_in[5];
    const void* W1 = d_in[6];  const void* b1 = d_in[7];
    const void* W2 = d_in[8];  const void* b2 = d_in[9];
    const void* W3 = d_in[10]; const void* b3 = d_in[11];

    // ---- workspace layout (bf16 elems; 16B flag header), ~96 MB ----
    bf16* ws    = (bf16*)d_ws;
    int*  flagp = (int*)d_ws;
    bf16* wslot = ws + 8;                    // 16777216: one bf16 weight at a time
    bf16* R     = ws + 8 + 16777216;         // 33554432-elem multi-use region
    bf16* inbuf = R;                         //   8388608: k/v/imf bf16, serially
    bf16* vproj = R + 8388608;               //   8388608 (dead after transpose)
    bf16* imfp  = R + 16777216;              //   8388608 (dead after transpose)
    bf16* s1    = R;                         //  33554432 (after inbuf/vproj/imfp die)
    bf16* xcat  = R;                         //  overlays s1 (dead after p@imf GEMM)

    // ---- d_out (134 MB) multi-duty until the final GEMM rewrites it all ----
    bf16* obase = (bf16*)d_out;
    bf16* qproj = obase;                     // 33554432 (dead after scores GEMM)
    bf16* qbf   = obase + 33554432;          // 33554432 (dead after qproj GEMM)
    bf16* kproj = obase + 33554432;          //  8388608 (lives where qbf died)
    bf16* vT    = obase + 41943040;          //  8388608
    bf16* imfT  = obase + 50331648;          //  8388608
    bf16* s2    = obase;                     // 33554432 (lives where qproj died)

    const float inv_sqrt_dk = 0.04419417382415922f;  // 1/sqrt(512)

    // 0: decide external dtype (fp32 vs bf16) from query's bit patterns
    sniff_dtype<<<1, 64, 0, stream>>>((const uint32_t*)query, flagp);

    // ---- Q path: convert, project (256^2 8-phase: 16x32 = 512 WGs) ----
    cvt_to_bf16<<<16384, 256, 0, stream>>>(query, qbf, flagp);
    cvt_to_bf16<<<8192, 256, 0, stream>>>(W0, wslot, flagp);
    gemm256<<<dim3(16, 32, 1), 512, 0, stream>>>(qbf, wslot, qproj, b0,
        4096, 4096, 4096, 4096, 1.f, 0,0,0,0,0,0, flagp, 1);
    // ---- K path (128^2 kernel: M=2048 keeps full-machine occupancy) ----
    cvt_to_bf16<<<4096, 256, 0, stream>>>(key, inbuf, flagp);
    cvt_to_bf16<<<8192, 256, 0, stream>>>(W1, wslot, flagp);
    gemm_bt<<<dim3(32, 16, 1), 256, 0, stream>>>(inbuf, wslot, kproj, b1,
        4096, 4096, 4096, 4096, 1.f, 0,0,0,0,0,0, flagp, 1);
    // ---- V path ----
    cvt_to_bf16<<<4096, 256, 0, stream>>>(value, inbuf, flagp);
    cvt_to_bf16<<<8192, 256, 0, stream>>>(W2, wslot, flagp);
    gemm_bt<<<dim3(32, 16, 1), 256, 0, stream>>>(inbuf, wslot, vproj, b2,
        4096, 4096, 4096, 4096, 1.f, 0,0,0,0,0,0, flagp, 1);
    // ---- imf path ----
    cvt_to_bf16<<<4096, 256, 0, stream>>>(imf, inbuf, flagp);
    cvt_to_bf16<<<8192, 256, 0, stream>>>(W3, wslot, flagp);
    gemm_bt<<<dim3(32, 16, 1), 256, 0, stream>>>(inbuf, wslot, imfp, b3,
        4096, 4096, 4096, 4096, 1.f, 0,0,0,0,0,0, flagp, 1);

    // ---- per-head transposes so the @imf and @v einsums become A·B^T ----
    transpose_heads<<<dim3(16, 16, 32), dim3(32, 8), 0, stream>>>(vproj, vT);
    transpose_heads<<<dim3(16, 16, 32), dim3(32, 8), 0, stream>>>(imfp, imfT);

    // ---- scores = q·k^T / sqrt(dk)  (2x8x32 = 512 WGs) ----
    gemm256<<<dim3(2, 8, 32), 512, 0, stream>>>(qproj, kproj, s1, nullptr,
        512, 4096, 4096, 512, inv_sqrt_dk,
        (long long)SQ_*DM_, (long long)DK_, (long long)SK_*DM_, (long long)DK_,
        (long long)H_*SQ_*SK_, (long long)SQ_*SK_, flagp, 0);
    softmax512<<<dim3(16384), 256, 0, stream>>>(s1);
    // ---- s2 = p @ imf_h (overwrites dead qproj in d_out) ----
    gemm256<<<dim3(2, 8, 32), 512, 0, stream>>>(s1, imfT, s2, nullptr,
        512, 512, 512, 512, 1.f,
        (long long)H_*SQ_*SK_, (long long)SQ_*SK_, (long long)H_*DK_*SK_, (long long)DK_*SK_,
        (long long)H_*SQ_*SK_, (long long)SQ_*SK_, flagp, 0);
    softmax512<<<dim3(16384), 256, 0, stream>>>(s2);
    // ---- x = im_attn @ v_h -> concat-head layout (xcat overlays dead s1) ----
    gemm256<<<dim3(2, 8, 32), 512, 0, stream>>>(s2, vT, xcat, nullptr,
        512, 512, 512, 4096, 1.f,
        (long long)H_*SQ_*SK_, (long long)SQ_*SK_, (long long)H_*DK_*SK_, (long long)DK_*SK_,
        (long long)SQ_*DM_, (long long)DK_, flagp, 0);
    // ---- out = xcat @ W3^T + b3 (re-convert shared W3; fp32 store per flag) ----
    cvt_to_bf16<<<8192, 256, 0, stream>>>(W3, wslot, flagp);
    gemm256<<<dim3(16, 32, 1), 512, 0, stream>>>(xcat, wslot, d_out, b3,
        4096, 4096, 4096, 4096, 1.f, 0,0,0,0,0,0, flagp, 3);
}

// Round 4
// 1604.737 us; speedup vs baseline: 1.0907x; 1.0907x over previous
//
#include <hip/hip_runtime.h>
#include <hip/hip_bf16.h>
#include <stdint.h>

// Problem constants (fixed by the reference)
#define B_   4
#define H_   8
#define SQ_  2048
#define SK_  512
#define DM_  4096
#define DK_  512

typedef __bf16 bf16;
typedef __bf16 bf16x8 __attribute__((ext_vector_type(8)));
typedef float  fx4    __attribute__((ext_vector_type(4)));

// address-space-qualified pointer types for global_load_lds
typedef __attribute__((address_space(1))) void gv_t;   // global
typedef __attribute__((address_space(3))) void lv_t;   // LDS

// ---------------------------------------------------------------------------
// Dtype sniffer (unchanged). flag=1 -> external tensors are fp32.
__global__ void sniff_dtype(const uint32_t* __restrict__ q, int* __restrict__ flag)
{
    const int l = threadIdx.x;  // 64 lanes
    int cnt = 0;
    #pragma unroll
    for (int i = 0; i < 4; ++i) {
        const uint32_t u = q[l * 4 + i];
        const int e = (u >> 7) & 0xFF;
        cnt += (e >= 100 && e <= 135) ? 1 : 0;
    }
    #pragma unroll
    for (int s = 1; s < 64; s <<= 1) cnt += __shfl_xor(cnt, s);
    if (l == 0) *flag = (cnt < 150) ? 1 : 0;
}

// ---------------------------------------------------------------------------
// One-time dtype normalization: fp32 -> bf16 (or bf16 passthrough copy).
__global__ __launch_bounds__(256) void cvt_to_bf16(
    const void* __restrict__ in, bf16* __restrict__ out, const int* __restrict__ flagp)
{
    const size_t i = ((size_t)blockIdx.x * 256 + threadIdx.x) * 8;
    if (*flagp) {
        const float4* p = (const float4*)((const float*)in + i);
        const float4 u0 = p[0], u1 = p[1];
        bf16x8 v;
        v[0] = (bf16)u0.x; v[1] = (bf16)u0.y; v[2] = (bf16)u0.z; v[3] = (bf16)u0.w;
        v[4] = (bf16)u1.x; v[5] = (bf16)u1.y; v[6] = (bf16)u1.z; v[7] = (bf16)u1.w;
        *(bf16x8*)(out + i) = v;
    } else {
        *(bf16x8*)(out + i) = *(const bf16x8*)((const bf16*)in + i);
    }
}

// ---------------------------------------------------------------------------
// 128^2-tile GEMM (verified rounds 0-1). Kept for the three M=2048 projections
// where a 256^2 grid would leave half the CUs idle.
__global__ __launch_bounds__(256, 3) void gemm_bt(
    const bf16* __restrict__ A, const bf16* __restrict__ Bt,
    void* __restrict__ Cv, const void* __restrict__ biasv,
    int K, int lda, int ldb, int ldc, float alpha,
    long long sAb, long long sAh, long long sBb, long long sBh,
    long long sCb, long long sCh,
    const int* __restrict__ flagp, int ebits)
{
    __shared__ bf16 sA[128 * 64];
    __shared__ bf16 sB[128 * 64];

    const int fl = ebits ? *flagp : 0;
    const bool bias32 = fl && (ebits & 1);
    const bool c32    = fl && (ebits & 2);

    const int z = blockIdx.z;
    const int bz = z >> 3, hz = z & 7;
    const bf16* Ab = A  + (size_t)bz * sAb + (size_t)hz * sAh;
    const bf16* Bb = Bt + (size_t)bz * sBb + (size_t)hz * sBh;
    const size_t offC = (size_t)bz * sCb + (size_t)hz * sCh;

    const int n0 = blockIdx.x * 128;
    const int m0 = blockIdx.y * 128;

    const int t = threadIdx.x;
    const int w = t >> 6, l = t & 63;
    const int lrow = l >> 3, lcol = l & 7;
    const int wm = (w >> 1) * 64, wn = (w & 1) * 64;
    const int ml = l & 15, quad = l >> 4;

    const bf16* pa[4];
    const bf16* pb[4];
    #pragma unroll
    for (int i = 0; i < 4; ++i) {
        const int c = w * 4 + i;
        const int r = c * 8 + lrow;
        const int jj = lcol ^ (r & 7);
        pa[i] = Ab + (size_t)(m0 + r) * lda + jj * 8;
        pb[i] = Bb + (size_t)(n0 + r) * ldb + jj * 8;
    }

    fx4 acc[4][4];
    const fx4 zero = {0.f, 0.f, 0.f, 0.f};
    #pragma unroll
    for (int i = 0; i < 4; ++i)
        #pragma unroll
        for (int j = 0; j < 4; ++j) acc[i][j] = zero;

    for (int kt = 0; kt < K; kt += 64) {
        #pragma unroll
        for (int i = 0; i < 4; ++i) {
            const int c = w * 4 + i;
            __builtin_amdgcn_global_load_lds((gv_t*)(pa[i] + kt), (lv_t*)(sA + c * 512), 16, 0, 0);
            __builtin_amdgcn_global_load_lds((gv_t*)(pb[i] + kt), (lv_t*)(sB + c * 512), 16, 0, 0);
        }
        __syncthreads();

        #pragma unroll
        for (int kk = 0; kk < 64; kk += 32) {
            bf16x8 af[4], bfr[4];
            const int jbase = (kk >> 3) + quad;
            #pragma unroll
            for (int mi = 0; mi < 4; ++mi) {
                const int r = wm + mi * 16 + ml;
                af[mi] = *(const bf16x8*)&sA[r * 64 + ((jbase ^ (r & 7)) << 3)];
            }
            #pragma unroll
            for (int ni = 0; ni < 4; ++ni) {
                const int r = wn + ni * 16 + ml;
                bfr[ni] = *(const bf16x8*)&sB[r * 64 + ((jbase ^ (r & 7)) << 3)];
            }
            #pragma unroll
            for (int mi = 0; mi < 4; ++mi)
                #pragma unroll
                for (int ni = 0; ni < 4; ++ni)
                    acc[mi][ni] = __builtin_amdgcn_mfma_f32_16x16x32_bf16(
                        af[mi], bfr[ni], acc[mi][ni], 0, 0, 0);
        }
        __syncthreads();
    }

    #pragma unroll
    for (int ni = 0; ni < 4; ++ni) {
        const int cg = n0 + wn + ni * 16 + ml;
        const float bv = biasv ? (bias32 ? ((const float*)biasv)[cg] : (float)((const bf16*)biasv)[cg]) : 0.f;
        #pragma unroll
        for (int mi = 0; mi < 4; ++mi) {
            const int rg = m0 + wm + mi * 16 + quad * 4;
            #pragma unroll
            for (int r = 0; r < 4; ++r) {
                const float val = acc[mi][ni][r] * alpha + bv;
                const size_t idx = offC + (size_t)(rg + r) * ldc + cg;
                if (c32) ((float*)Cv)[idx] = val;
                else     ((bf16*)Cv)[idx] = (bf16)val;
            }
        }
    }
}

// ---------------------------------------------------------------------------
// 256^2-tile pipelined GEMM, round 4: Gray-code fragment reuse.
// Round-3 post-mortem: 48 ds_read_b128/wave/K-tile (2x the unique data) made
// the kernel LDS-read-bound (4608 cyc LDS vs 2483 cyc MFMA per CU per K-tile,
// MfmaUtil ceiling 54%, measured 30%). Fix: quadrant order A0B0->A0B1->A1B1->
// A1B0 with B0/B1 each loaded once and A reloaded into the SAME af registers
// (WAR hazard pins the A1 reads after P1's MFMAs -- no fence needed).
// 24 reads/wave/K-tile -> LDS pipe (2304 cyc) < MFMA pipe (2483 cyc).
// B1/A1 read bundles issue in the TAIL of the preceding MFMA slot so the LDS
// pipe drains under MFMA issue. 5 barriers/K-tile (was 9). Boundary protocol
// (counted vmcnt(8), raw s_barrier, 2-ahead prefetch) unchanged from round 3.
#define ISSUE_TILE(tt, bb)                                                        \
    do {                                                                          \
        _Pragma("unroll")                                                         \
        for (int i_ = 0; i_ < 4; ++i_) {                                          \
            const int c_ = w * 4 + i_;                                            \
            __builtin_amdgcn_global_load_lds((gv_t*)(pa[i_] + (size_t)(tt) * 64), \
                (lv_t*)(&sm[bb][0][c_ * 512]), 16, 0, 0);                         \
            __builtin_amdgcn_global_load_lds((gv_t*)(pb[i_] + (size_t)(tt) * 64), \
                (lv_t*)(&sm[bb][1][c_ * 512]), 16, 0, 0);                         \
        }                                                                         \
    } while (0)

// fragment load: row fr, k-group j=kI*4+quad, XOR slot swizzle
#define LDS_FRAG(dst, base, fr, kI)                                               \
    dst = *(const bf16x8*)&base[(fr) * 64 + ((((kI) * 4 + quad) ^ ((fr) & 7)) << 3)]

__global__ __launch_bounds__(512, 2) void gemm256(
    const bf16* __restrict__ A, const bf16* __restrict__ Bt,
    void* __restrict__ Cv, const void* __restrict__ biasv,
    int K, int lda, int ldb, int ldc, float alpha,
    long long sAb, long long sAh, long long sBb, long long sBh,
    long long sCb, long long sCh,
    const int* __restrict__ flagp, int ebits)
{
    __shared__ bf16 sm[2][2][256 * 64];   // [buf][A/B][tile] = 128 KiB

    const int fl = ebits ? *flagp : 0;
    const bool bias32 = fl && (ebits & 1);
    const bool c32    = fl && (ebits & 2);

    // ---- XCD-bijective block swizzle (all grids here are %8==0) ----
    const int gX = gridDim.x, gY = gridDim.y;
    int idx = (blockIdx.z * gY + blockIdx.y) * gX + blockIdx.x;
    const int nwg = gX * gY * gridDim.z;
    if ((nwg & 7) == 0) idx = (idx & 7) * (nwg >> 3) + (idx >> 3);
    const int bx = idx % gX;
    const int tmpi = idx / gX;
    const int by = tmpi % gY;
    const int z  = tmpi / gY;

    const int bz = z >> 3, hz = z & 7;
    const bf16* Ab = A  + (size_t)bz * sAb + (size_t)hz * sAh;
    const bf16* Bb = Bt + (size_t)bz * sBb + (size_t)hz * sBh;
    const size_t offC = (size_t)bz * sCb + (size_t)hz * sCh;

    const int n0 = bx * 256;
    const int m0 = by * 256;

    const int t  = threadIdx.x;
    const int w  = t >> 6, l = t & 63;
    const int lrow = l >> 3, lcol = l & 7;          // staging decomposition
    const int wr = w >> 2, wc = w & 3;              // wave grid 2x4
    const int R0 = wr * 128, C0 = wc * 64;          // per-wave C sub-tile
    const int ml = l & 15, quad = l >> 4;           // MFMA fragment lanes

    // per-lane pre-swizzled global source pointers (4 chunks/tensor/wave)
    const bf16* pa[4];
    const bf16* pb[4];
    #pragma unroll
    for (int i = 0; i < 4; ++i) {
        const int c = w * 4 + i;
        const int r = c * 8 + lrow;
        const int jj = lcol ^ (r & 7);
        pa[i] = Ab + (size_t)(m0 + r) * lda + jj * 8;
        pb[i] = Bb + (size_t)(n0 + r) * ldb + jj * 8;
    }

    fx4 acc[8][4];
    const fx4 zero = {0.f, 0.f, 0.f, 0.f};
    #pragma unroll
    for (int i = 0; i < 8; ++i)
        #pragma unroll
        for (int j = 0; j < 4; ++j) acc[i][j] = zero;

    const int nt = K >> 6;   // K-tiles of 64

    // ---- prologue: fill both buffers; keep tile 1's 8 loads in flight ----
    ISSUE_TILE(0, 0);
    ISSUE_TILE(1, 1);
    asm volatile("s_waitcnt vmcnt(8)" ::: "memory");
    asm volatile("s_barrier" ::: "memory");

    for (int tt = 0; tt < nt; ++tt) {
        const int b = tt & 1;
        const bf16* sA = sm[b][0];
        const bf16* sB = sm[b][1];

        bf16x8 af[4][2];    // A half (reused: A0 then A1, same registers)
        bf16x8 b0f[2][2];   // B cols C0..C0+31   (held whole tile)
        bf16x8 b1f[2][2];   // B cols C0+32..C0+63 (held from X1 on)

        // ---- X0: reads A0 (8) + B0 (4) ----
        #pragma unroll
        for (int im = 0; im < 4; ++im)
            #pragma unroll
            for (int kI = 0; kI < 2; ++kI)
                LDS_FRAG(af[im][kI], sA, R0 + im * 16 + ml, kI);
        #pragma unroll
        for (int in = 0; in < 2; ++in)
            #pragma unroll
            for (int kI = 0; kI < 2; ++kI)
                LDS_FRAG(b0f[in][kI], sB, C0 + in * 16 + ml, kI);
        asm volatile("s_barrier" ::: "memory");

        // ---- X1: MFMA P0 = A0 x B0 -> acc[0..3][0..1]; tail: B1 reads ----
        __builtin_amdgcn_s_setprio(1);
        #pragma unroll
        for (int kI = 0; kI < 2; ++kI)
            #pragma unroll
            for (int im = 0; im < 4; ++im)
                #pragma unroll
                for (int in = 0; in < 2; ++in)
                    acc[im][in] = __builtin_amdgcn_mfma_f32_16x16x32_bf16(
                        af[im][kI], b0f[in][kI], acc[im][in], 0, 0, 0);
        __builtin_amdgcn_s_setprio(0);
        #pragma unroll
        for (int in = 0; in < 2; ++in)
            #pragma unroll
            for (int kI = 0; kI < 2; ++kI)
                LDS_FRAG(b1f[in][kI], sB, C0 + 32 + in * 16 + ml, kI);
        asm volatile("s_barrier" ::: "memory");

        // ---- X2: MFMA P1 = A0 x B1 -> acc[0..3][2..3]; tail: A1 reads ----
        // (A1 writes af: WAR on P1's operands keeps the reads after the MFMAs)
        __builtin_amdgcn_s_setprio(1);
        #pragma unroll
        for (int kI = 0; kI < 2; ++kI)
            #pragma unroll
            for (int im = 0; im < 4; ++im)
                #pragma unroll
                for (int in = 0; in < 2; ++in)
                    acc[im][2 + in] = __builtin_amdgcn_mfma_f32_16x16x32_bf16(
                        af[im][kI], b1f[in][kI], acc[im][2 + in], 0, 0, 0);
        __builtin_amdgcn_s_setprio(0);
        #pragma unroll
        for (int im = 0; im < 4; ++im)
            #pragma unroll
            for (int kI = 0; kI < 2; ++kI)
                LDS_FRAG(af[im][kI], sA, R0 + 64 + im * 16 + ml, kI);
        asm volatile("s_barrier" ::: "memory");

        // ---- X3: MFMA P2 = A1 x B1 -> acc[4..7][2..3] ----
        __builtin_amdgcn_s_setprio(1);
        #pragma unroll
        for (int kI = 0; kI < 2; ++kI)
            #pragma unroll
            for (int im = 0; im < 4; ++im)
                #pragma unroll
                for (int in = 0; in < 2; ++in)
                    acc[4 + im][2 + in] = __builtin_amdgcn_mfma_f32_16x16x32_bf16(
                        af[im][kI], b1f[in][kI], acc[4 + im][2 + in], 0, 0, 0);
        __builtin_amdgcn_s_setprio(0);
        asm volatile("s_barrier" ::: "memory");

        // ---- X4: MFMA P3 = A1 x B0 -> acc[4..7][0..1]; boundary ----
        __builtin_amdgcn_s_setprio(1);
        #pragma unroll
        for (int kI = 0; kI < 2; ++kI)
            #pragma unroll
            for (int im = 0; im < 4; ++im)
                #pragma unroll
                for (int in = 0; in < 2; ++in)
                    acc[4 + im][in] = __builtin_amdgcn_mfma_f32_16x16x32_bf16(
                        af[im][kI], b0f[in][kI], acc[4 + im][in], 0, 0, 0);
        __builtin_amdgcn_s_setprio(0);

        if (tt + 1 >= nt) break;
        // buf b is dead: last buf-b ds_reads (A1, X2) completed before P2's
        // MFMAs; all waves passed the X3-end barrier before anyone issues here.
        if (tt + 2 < nt) {
            ISSUE_TILE(tt + 2, b);
            asm volatile("s_waitcnt vmcnt(8)" ::: "memory");  // tt+1 landed; tt+2 in flight
        } else {
            asm volatile("s_waitcnt vmcnt(0)" ::: "memory");  // epilogue drain
        }
        asm volatile("s_barrier" ::: "memory");
    }

    // ---- epilogue: C/D layout col=lane&15, row=(lane>>4)*4+reg ----
    #pragma unroll
    for (int ni = 0; ni < 4; ++ni) {
        const int cg = n0 + C0 + ni * 16 + ml;
        const float bv = biasv ? (bias32 ? ((const float*)biasv)[cg] : (float)((const bf16*)biasv)[cg]) : 0.f;
        #pragma unroll
        for (int mi = 0; mi < 8; ++mi) {
            const int rg = m0 + R0 + mi * 16 + quad * 4;
            #pragma unroll
            for (int r = 0; r < 4; ++r) {
                const float val = acc[mi][ni][r] * alpha + bv;
                const size_t idx = offC + (size_t)(rg + r) * ldc + cg;
                if (c32) ((float*)Cv)[idx] = val;
                else     ((bf16*)Cv)[idx] = (bf16)val;
            }
        }
    }
}

// In-place row softmax, rows of exactly 512 bf16. One wave per row (8 elems/lane).
__global__ __launch_bounds__(256) void softmax512(bf16* __restrict__ buf)
{
    const int row = blockIdx.x * 4 + (threadIdx.x >> 6);
    const int l = threadIdx.x & 63;
    bf16* p = buf + (size_t)row * 512 + l * 8;
    bf16x8 v = *(const bf16x8*)p;
    float f[8];
    float mx = -1e30f;
    #pragma unroll
    for (int j = 0; j < 8; ++j) {
        f[j] = (float)v[j];
        if (!(fabsf(f[j]) < 1e30f)) f[j] = -1e9f;   // NaN/Inf guard
        mx = fmaxf(mx, f[j]);
    }
    #pragma unroll
    for (int s = 1; s < 64; s <<= 1) mx = fmaxf(mx, __shfl_xor(mx, s));
    float sum = 0.f;
    #pragma unroll
    for (int j = 0; j < 8; ++j) { f[j] = __expf(f[j] - mx); sum += f[j]; }
    #pragma unroll
    for (int s = 1; s < 64; s <<= 1) sum += __shfl_xor(sum, s);
    const float inv = 1.f / sum;
    #pragma unroll
    for (int j = 0; j < 8; ++j) v[j] = (bf16)(f[j] * inv);
    *(bf16x8*)p = v;
}

// out[z][d][s] = in[b][s][h*512+d], z = b*8+h. 32x32 tiles via LDS. (internal bf16)
__global__ __launch_bounds__(256) void transpose_heads(
    const bf16* __restrict__ in, bf16* __restrict__ out)
{
    __shared__ bf16 tile[32][33];
    const int z = blockIdx.z, b = z >> 3, h = z & 7;
    const int s0 = blockIdx.x * 32, d0 = blockIdx.y * 32;
    const int tx = threadIdx.x, ty = threadIdx.y;   // 32 x 8
    #pragma unroll
    for (int j = 0; j < 4; ++j) {
        const int s = s0 + ty + j * 8;
        tile[ty + j * 8][tx] = in[(size_t)b * SK_ * DM_ + (size_t)s * DM_ + h * DK_ + d0 + tx];
    }
    __syncthreads();
    #pragma unroll
    for (int j = 0; j < 4; ++j) {
        const int d = d0 + ty + j * 8;
        out[(size_t)z * DK_ * SK_ + (size_t)d * SK_ + s0 + tx] = tile[tx][ty + j * 8];
    }
}

extern "C" void kernel_launch(void* const* d_in, const int* in_sizes, int n_in,
                              void* d_out, int out_size, void* d_ws, size_t ws_size,
                              hipStream_t stream)
{
    const void* query = d_in[0];
    const void* key   = d_in[1];
    const void* value = d_in[2];
    const void* imf   = d_in[3];
    const void* W0 = d_in[4];  const void* b0 = d_in[5];
    const void* W1 = d_in[6];  const void* b1 = d_in[7];
    const void* W2 = d_in[8];  const void* b2 = d_in[9];
    const void* W3 = d_in[10]; const void* b3 = d_in[11];

    // ---- workspace layout (bf16 elems; 16B flag header), ~96 MB ----
    bf16* ws    = (bf16*)d_ws;
    int*  flagp = (int*)d_ws;
    bf16* wslot = ws + 8;                    // 16777216: one bf16 weight at a time
    bf16* R     = ws + 8 + 16777216;         // 33554432-elem multi-use region
    bf16* inbuf = R;                         //   8388608: k/v/imf bf16, serially
    bf16* vproj = R + 8388608;               //   8388608 (dead after transpose)
    bf16* imfp  = R + 16777216;              //   8388608 (dead after transpose)
    bf16* s1    = R;                         //  33554432 (after inbuf/vproj/imfp die)
    bf16* xcat  = R;                         //  overlays s1 (dead after p@imf GEMM)

    // ---- d_out (134 MB) multi-duty until the final GEMM rewrites it all ----
    bf16* obase = (bf16*)d_out;
    bf16* qproj = obase;                     // 33554432 (dead after scores GEMM)
    bf16* qbf   = obase + 33554432;          // 33554432 (dead after qproj GEMM)
    bf16* kproj = obase + 33554432;          //  8388608 (lives where qbf died)
    bf16* vT    = obase + 41943040;          //  8388608
    bf16* imfT  = obase + 50331648;          //  8388608
    bf16* s2    = obase;                     // 33554432 (lives where qproj died)

    const float inv_sqrt_dk = 0.04419417382415922f;  // 1/sqrt(512)

    // 0: decide external dtype (fp32 vs bf16) from query's bit patterns
    sniff_dtype<<<1, 64, 0, stream>>>((const uint32_t*)query, flagp);

    // ---- Q path: convert, project (256^2 pipelined: 16x32 = 512 WGs) ----
    cvt_to_bf16<<<16384, 256, 0, stream>>>(query, qbf, flagp);
    cvt_to_bf16<<<8192, 256, 0, stream>>>(W0, wslot, flagp);
    gemm256<<<dim3(16, 32, 1), 512, 0, stream>>>(qbf, wslot, qproj, b0,
        4096, 4096, 4096, 4096, 1.f, 0,0,0,0,0,0, flagp, 1);
    // ---- K path (128^2 kernel: M=2048 keeps full-machine occupancy) ----
    cvt_to_bf16<<<4096, 256, 0, stream>>>(key, inbuf, flagp);
    cvt_to_bf16<<<8192, 256, 0, stream>>>(W1, wslot, flagp);
    gemm_bt<<<dim3(32, 16, 1), 256, 0, stream>>>(inbuf, wslot, kproj, b1,
        4096, 4096, 4096, 4096, 1.f, 0,0,0,0,0,0, flagp, 1);
    // ---- V path ----
    cvt_to_bf16<<<4096, 256, 0, stream>>>(value, inbuf, flagp);
    cvt_to_bf16<<<8192, 256, 0, stream>>>(W2, wslot, flagp);
    gemm_bt<<<dim3(32, 16, 1), 256, 0, stream>>>(inbuf, wslot, vproj, b2,
        4096, 4096, 4096, 4096, 1.f, 0,0,0,0,0,0, flagp, 1);
    // ---- imf path ----
    cvt_to_bf16<<<4096, 256, 0, stream>>>(imf, inbuf, flagp);
    cvt_to_bf16<<<8192, 256, 0, stream>>>(W3, wslot, flagp);
    gemm_bt<<<dim3(32, 16, 1), 256, 0, stream>>>(inbuf, wslot, imfp, b3,
        4096, 4096, 4096, 4096, 1.f, 0,0,0,0,0,0, flagp, 1);

    // ---- per-head transposes so the @imf and @v einsums become A·B^T ----
    transpose_heads<<<dim3(16, 16, 32), dim3(32, 8), 0, stream>>>(vproj, vT);
    transpose_heads<<<dim3(16, 16, 32), dim3(32, 8), 0, stream>>>(imfp, imfT);

    // ---- scores = q·k^T / sqrt(dk)  (2x8x32 = 512 WGs) ----
    gemm256<<<dim3(2, 8, 32), 512, 0, stream>>>(qproj, kproj, s1, nullptr,
        512, 4096, 4096, 512, inv_sqrt_dk,
        (long long)SQ_*DM_, (long long)DK_, (long long)SK_*DM_, (long long)DK_,
        (long long)H_*SQ_*SK_, (long long)SQ_*SK_, flagp, 0);
    softmax512<<<dim3(16384), 256, 0, stream>>>(s1);
    // ---- s2 = p @ imf_h (overwrites dead qproj in d_out) ----
    gemm256<<<dim3(2, 8, 32), 512, 0, stream>>>(s1, imfT, s2, nullptr,
        512, 512, 512, 512, 1.f,
        (long long)H_*SQ_*SK_, (long long)SQ_*SK_, (long long)H_*DK_*SK_, (long long)DK_*SK_,
        (long long)H_*SQ_*SK_, (long long)SQ_*SK_, flagp, 0);
    softmax512<<<dim3(16384), 256, 0, stream>>>(s2);
    // ---- x = im_attn @ v_h -> concat-head layout (xcat overlays dead s1) ----
    gemm256<<<dim3(2, 8, 32), 512, 0, stream>>>(s2, vT, xcat, nullptr,
        512, 512, 512, 4096, 1.f,
        (long long)H_*SQ_*SK_, (long long)SQ_*SK_, (long long)H_*DK_*SK_, (long long)DK_*SK_,
        (long long)SQ_*DM_, (long long)DK_, flagp, 0);
    // ---- out = xcat @ W3^T + b3 (re-convert shared W3; fp32 store per flag) ----
    cvt_to_bf16<<<8192, 256, 0, stream>>>(W3, wslot, flagp);
    gemm256<<<dim3(16, 32, 1), 512, 0, stream>>>(xcat, wslot, d_out, b3,
        4096, 4096, 4096, 4096, 1.f, 0,0,0,0,0,0, flagp, 3);
}